// Round 7
// baseline (331.949 us; speedup 1.0000x reference)
//
#include <hip/hip_runtime.h>
#include <hip/hip_cooperative_groups.h>

namespace cg = cooperative_groups;

// Predictive-coding graph message passing, MI355X — round 7.
// R6 failed: unchecked hipLaunchCooperativeKernel error (1024-thr blocks need
// VGPR<=64 for 2-block/CU co-residency; waves-per-EU hint is best-effort).
// R7: 512-thr blocks (co-residency needs only VGPR<=128 — huge slack), host
// pre-check via occupancy query before enqueueing coop launch, and a guarded
// 4-dispatch fallback (R5 structure, memset folded into k_init).

static constexpr int kB = 32, kLogB = 5;
static constexpr int kT = 8;            // nodes per bin
static constexpr int kNumBins = 512;    // N / kT (N = 4096)
static constexpr int kCap = 1408;       // slots/bin: mean 1024, +12 sigma
static constexpr int kPad = 36;         // replica row stride (conflict-free)
static constexpr int kSlots = 16;       // 512 threads / 32 lanes
static constexpr int kChunk = 1024;     // edges per binning block/iteration
static constexpr int kLdsF = kSlots * kT * kPad;   // 4608 floats = 18.4 KB

// ---- Phase helpers (block-scope; 512 threads) ------------------------------

__device__ __forceinline__ void init_tile(float* ldsf, const float* __restrict__ x,
    float* __restrict__ x_t, float* __restrict__ fx_t, int N, int g) {
  float (*tile)[65] = (float(*)[65])ldsf;        // 32 x 65 = 2080 floats
  int tid = threadIdx.x;
  int n0 = g * 64;
  for (int k = tid; k < 32 * 64; k += 512) {     // coalesced 256B rows
    int b = k >> 6, n = k & 63;
    tile[b][n] = x[b * N + n0 + n];
  }
  __syncthreads();
  for (int k = tid; k < 64 * 32; k += 512) {     // coalesced t-layout write
    int n = k >> 5, b = k & 31;
    float xv = tile[b][n];
    int j = (n0 + n) * kB + b;
    x_t[j] = xv;
    fx_t[j] = tanhf(xv);
  }
}

__device__ __forceinline__ void bin_chunk(float* ldsf,
    const int* __restrict__ esrc, const int* __restrict__ edst,
    const float* __restrict__ w, uint2* __restrict__ binsA,
    uint2* __restrict__ binsB, int* __restrict__ cursA,
    int* __restrict__ cursB, int E, int c) {
  int* histA = (int*)ldsf;                       // 512
  int* histB = histA + kNumBins;                 // 512
  int* baseA = histB + kNumBins;                 // 512
  int* baseB = baseA + kNumBins;                 // 512 (8 KB)
  int tid = threadIdx.x;                         // == bin id (512 threads)
  histA[tid] = 0; histB[tid] = 0;
  __syncthreads();
  int e0 = c * kChunk;
  int nloc = min(kChunk, E - e0);
  int k0 = tid, k1 = tid + 512;                  // 2 edges/thread, registers
  int s0 = 0, d0 = 0, s1 = 0, d1 = 0;
  unsigned a0 = 0, b0 = 0, a1 = 0, b1 = 0;
  bool h0 = k0 < nloc, h1 = k1 < nloc;
  if (h0) {
    s0 = esrc[e0 + k0]; d0 = edst[e0 + k0];
    a0 = atomicAdd(&histA[d0 >> 3], 1);          // int LDS atomic: native
    b0 = atomicAdd(&histB[s0 >> 3], 1);
  }
  if (h1) {
    s1 = esrc[e0 + k1]; d1 = edst[e0 + k1];
    a1 = atomicAdd(&histA[d1 >> 3], 1);
    b1 = atomicAdd(&histB[s1 >> 3], 1);
  }
  __syncthreads();
  baseA[tid] = atomicAdd(&cursA[tid], histA[tid]);
  baseB[tid] = atomicAdd(&cursB[tid], histB[tid]);
  __syncthreads();
  if (h0) {
    unsigned wu = __float_as_uint(w[e0 + k0]);
    int bin = d0 >> 3; int p = baseA[bin] + (int)a0;
    if (p < kCap) binsA[(size_t)bin * kCap + p] = make_uint2(((unsigned)s0 << 8) | (d0 & 7), wu);
    bin = s0 >> 3; p = baseB[bin] + (int)b0;
    if (p < kCap) binsB[(size_t)bin * kCap + p] = make_uint2(((unsigned)d0 << 8) | (s0 & 7), wu);
  }
  if (h1) {
    unsigned wu = __float_as_uint(w[e0 + k1]);
    int bin = d1 >> 3; int p = baseA[bin] + (int)a1;
    if (p < kCap) binsA[(size_t)bin * kCap + p] = make_uint2(((unsigned)s1 << 8) | (d1 & 7), wu);
    bin = s1 >> 3; p = baseB[bin] + (int)b1;
    if (p < kCap) binsB[(size_t)bin * kCap + p] = make_uint2(((unsigned)d1 << 8) | (s1 & 7), wu);
  }
}

// One bin: private per-half-wave LDS replicas (no atomics), gather pipelined
// 3 deep (records 4 deep), 16-way tree-sum epilogue.
__device__ __forceinline__ void accum_bin(float* ldsf,
    const uint2* __restrict__ bins, const int* __restrict__ cursors,
    const float* __restrict__ vals, const float* __restrict__ x_t,
    const float* __restrict__ fx_t, float* __restrict__ eps_t,
    float* __restrict__ out, int N, int t, int mode) {
  int tid = threadIdx.x, b = tid & 31, slot = tid >> 5;   // 16 slots
  float* my = ldsf + slot * (kT * kPad);
#pragma unroll
  for (int l = 0; l < kT; l++) my[l * kPad + b] = 0.0f;   // private region
  int cnt = min(cursors[t], kCap);
  const uint2* bp = bins + (size_t)t * kCap;
  int i = slot;
  uint2 r0 = (i      < cnt) ? bp[i]      : make_uint2(0u, 0u);
  uint2 r1 = (i + 16 < cnt) ? bp[i + 16] : make_uint2(0u, 0u);
  uint2 r2 = (i + 32 < cnt) ? bp[i + 32] : make_uint2(0u, 0u);
  uint2 r3 = (i + 48 < cnt) ? bp[i + 48] : make_uint2(0u, 0u);
  float v0 = (i      < cnt) ? vals[((r0.x >> 8) << kLogB) + b] : 0.0f;
  float v1 = (i + 16 < cnt) ? vals[((r1.x >> 8) << kLogB) + b] : 0.0f;
  float v2 = (i + 32 < cnt) ? vals[((r2.x >> 8) << kLogB) + b] : 0.0f;
  while (i < cnt) {
    uint2 r4 = (i + 64 < cnt) ? bp[i + 64] : make_uint2(0u, 0u);
    float v3 = (i + 48 < cnt) ? vals[((r3.x >> 8) << kLogB) + b] : 0.0f;
    my[(r0.x & 7) * kPad + b] += __uint_as_float(r0.y) * v0;  // <=2-way: free
    r0 = r1; r1 = r2; r2 = r3; r3 = r4;
    v0 = v1; v1 = v2; v2 = v3;
    i += 16;
  }
  __syncthreads();
  if (tid < kT * kB) {                           // 256 lanes
    int local = tid & 7, bb = tid >> 3;          // local-fast: 32B store runs
    float s = 0.0f;
#pragma unroll
    for (int sl = 0; sl < kSlots; sl++) s += ldsf[sl * (kT * kPad) + local * kPad + bb];
    int n = t * kT + local;
    int j = n * kB + bb;
    if (mode == 0) {
      out[bb * N + n] = s;                       // mu (batch-major)
      eps_t[j] = x_t[j] - s;
    } else {
      float fx = fx_t[j];
      out[bb * N + n] = fmaf(1.0f - fx * fx, s, -eps_t[j]);   // dx
    }
  }
}

// ---- Cooperative mega-kernel ----------------------------------------------

__global__ void __launch_bounds__(512, 4) k_fused(
    const float* __restrict__ x, const float* __restrict__ w,
    const int* __restrict__ esrc, const int* __restrict__ edst,
    float* __restrict__ x_t, float* __restrict__ fx_t,
    float* __restrict__ eps_t, int* __restrict__ cursA,
    int* __restrict__ cursB, uint2* __restrict__ binsA,
    uint2* __restrict__ binsB, float* __restrict__ out_mu,
    float* __restrict__ out_dx, int N, int E) {
  cg::grid_group grid = cg::this_grid();
  __shared__ float ldsf[kLdsF];                  // 18.4 KB, aliased per phase
  int blk = blockIdx.x, G = gridDim.x, tid = threadIdx.x;

  if (blk == 0 && tid < kNumBins) { cursA[tid] = 0; cursB[tid] = 0; }
  int nTiles = N >> 6;
  for (int g = blk; g < nTiles; g += G) {
    __syncthreads();                             // LDS reuse guard
    init_tile(ldsf, x, x_t, fx_t, N, g);
  }
  grid.sync();

  int nChunks = (E + kChunk - 1) / kChunk;
  for (int c = blk; c < nChunks; c += G) {
    __syncthreads();
    bin_chunk(ldsf, esrc, edst, w, binsA, binsB, cursA, cursB, E, c);
  }
  grid.sync();

  for (int t = blk; t < kNumBins; t += G) {
    __syncthreads();
    accum_bin(ldsf, binsA, cursA, fx_t, x_t, fx_t, eps_t, out_mu, N, t, 0);
  }
  grid.sync();

  for (int t = blk; t < kNumBins; t += G) {
    __syncthreads();
    accum_bin(ldsf, binsB, cursB, eps_t, x_t, fx_t, eps_t, out_dx, N, t, 1);
  }
}

// ---- Fallback 4-dispatch path ---------------------------------------------

__global__ void __launch_bounds__(512) k_init(
    const float* __restrict__ x, float* __restrict__ x_t,
    float* __restrict__ fx_t, int* __restrict__ cursA,
    int* __restrict__ cursB, int N) {
  __shared__ float ldsf[32 * 65];
  if (blockIdx.x == 0 && threadIdx.x < kNumBins) {
    cursA[threadIdx.x] = 0; cursB[threadIdx.x] = 0;
  }
  init_tile(ldsf, x, x_t, fx_t, N, blockIdx.x);
}

__global__ void __launch_bounds__(512) k_bin(
    const int* __restrict__ esrc, const int* __restrict__ edst,
    const float* __restrict__ w, uint2* __restrict__ binsA,
    uint2* __restrict__ binsB, int* __restrict__ cursA,
    int* __restrict__ cursB, int E) {
  __shared__ float ldsf[4 * kNumBins];           // hist/base
  bin_chunk(ldsf, esrc, edst, w, binsA, binsB, cursA, cursB, E, blockIdx.x);
}

__global__ void __launch_bounds__(512) k_accum(
    const uint2* __restrict__ bins, const int* __restrict__ cursors,
    const float* __restrict__ vals, const float* __restrict__ x_t,
    const float* __restrict__ fx_t, float* __restrict__ eps_t,
    float* __restrict__ out, int N, int mode) {
  __shared__ float ldsf[kLdsF];
  accum_bin(ldsf, bins, cursors, vals, x_t, fx_t, eps_t, out, N, blockIdx.x, mode);
}

extern "C" void kernel_launch(void* const* d_in, const int* in_sizes, int n_in,
                              void* d_out, int out_size, void* d_ws, size_t ws_size,
                              hipStream_t stream) {
  const float* x    = (const float*)d_in[0];
  const float* w    = (const float*)d_in[1];
  const int*   esrc = (const int*)d_in[2];
  const int*   edst = (const int*)d_in[3];

  int BN = in_sizes[0];                // 131072
  int E  = in_sizes[1];                // 524288
  int N  = BN / kB;                    // 4096

  float* ws    = (float*)d_ws;
  float* x_t   = ws;                   // [BN]
  float* fx_t  = ws + (size_t)BN;      // [BN]
  float* eps_t = ws + 2 * (size_t)BN;  // [BN]
  int*   cursA = (int*)(ws + 3 * (size_t)BN);
  int*   cursB = cursA + kNumBins;
  uint2* binsA = (uint2*)(cursB + kNumBins);          // 5.77 MB
  uint2* binsB = binsA + (size_t)kNumBins * kCap;     // 5.77 MB

  float* out_mu = (float*)d_out;
  float* out_dx = (float*)d_out + BN;

  // Host-only queries (graph-capture-safe; no stream interaction).
  int dev = 0; (void)hipGetDevice(&dev);
  int coop = 0, ncu = 0, nb = 0;
  (void)hipDeviceGetAttribute(&coop, hipDeviceAttributeCooperativeLaunch, dev);
  (void)hipDeviceGetAttribute(&ncu, hipDeviceAttributeMultiprocessorCount, dev);
  (void)hipOccupancyMaxActiveBlocksPerMultiprocessor(&nb, (const void*)k_fused, 512, 0);

  if (coop && (long)nb * (long)ncu >= (long)kNumBins) {
    void* args[] = {&x, &w, &esrc, &edst, &x_t, &fx_t, &eps_t,
                    &cursA, &cursB, &binsA, &binsB, &out_mu, &out_dx, &N, &E};
    hipError_t err = hipLaunchCooperativeKernel((const void*)k_fused,
                                                dim3(kNumBins), dim3(512),
                                                args, 0, stream);
    if (err == hipSuccess) return;
    (void)hipGetLastError();                     // clear sticky error, fall back
  }

  // Fallback: 4 dispatches, stream-ordered.
  k_init<<<N / 64, 512, 0, stream>>>(x, x_t, fx_t, cursA, cursB, N);
  k_bin<<<(E + kChunk - 1) / kChunk, 512, 0, stream>>>(esrc, edst, w, binsA,
                                                       binsB, cursA, cursB, E);
  k_accum<<<kNumBins, 512, 0, stream>>>(binsA, cursA, fx_t, x_t, fx_t, eps_t,
                                        out_mu, N, 0);
  k_accum<<<kNumBins, 512, 0, stream>>>(binsB, cursB, eps_t, x_t, fx_t, eps_t,
                                        out_dx, N, 1);
}

// Round 8
// 118.501 us; speedup vs baseline: 2.8012x; 2.8012x over previous
//
#include <hip/hip_runtime.h>

// Predictive-coding graph message passing, MI355X — round 8.
// R7 lesson: cooperative mega-kernel = 255us for work that costs ~70us as
// separate dispatches (grid.sync does device-scope L2 flush per phase).
// R8: back to multi-dispatch. (1) binning with ZERO global atomics:
// deterministic per-block slices bins[row][bin][20], row = exclusive 2048-edge
// chunk per block (R5 had 262K contended cursor atomic-returns); (2) transpose
// fused into the bin kernel; (3) accum compacts records to LDS first (scan +
// copy), THEN runs the pipelined gather loop — breaks the record->gather
// dependent-load chain.

static constexpr int kB = 32, kLogB = 5;
static constexpr int kT = 8;             // nodes per bin
static constexpr int kNumBins = 512;     // N / kT (N = 4096)
static constexpr int kChunkE = 2048;     // edges per binning block (row)
static constexpr int kSlice = 20;        // slots per (row, bin): mean 4, +8sigma
static constexpr int kStageCap = 1280;   // records per bin: mean 1024, +8sigma
static constexpr int kPad = 36;          // replica row stride
static constexpr int kMaxRows = 256;     // E / kChunkE for E=524288

// ---- K1: fused transpose/tanh + dual deterministic binning ----------------
__global__ void __launch_bounds__(1024) k_binit(
    const float* __restrict__ x, const float* __restrict__ w,
    const int* __restrict__ esrc, const int* __restrict__ edst,
    float* __restrict__ x_t, float* __restrict__ fx_t,
    uint2* __restrict__ binsA, uint2* __restrict__ binsB,
    unsigned short* __restrict__ cntA, unsigned short* __restrict__ cntB,
    int N, int E, int nrows) {
  __shared__ int cA[kNumBins], cB[kNumBins];
  __shared__ float tile[32][65];
  int tid = threadIdx.x, blk = blockIdx.x;

  // Binning phase: block = row blk, exclusive slice region (no global atomics).
  if (blk < nrows) {
    for (int t = tid; t < kNumBins; t += 1024) { cA[t] = 0; cB[t] = 0; }
    __syncthreads();
    int e0 = blk * kChunkE;
#pragma unroll
    for (int k = 0; k < kChunkE / 1024; k++) {
      int e = e0 + k * 1024 + tid;
      if (e < E) {
        int s = esrc[e], d = edst[e];
        unsigned wu = __float_as_uint(w[e]);
        int slotA = atomicAdd(&cA[d >> 3], 1);        // LDS int atomic: native
        if (slotA < kSlice)
          binsA[((size_t)blk * kNumBins + (d >> 3)) * kSlice + slotA] =
              make_uint2(((unsigned)s << 8) | (d & 7), wu);
        int slotB = atomicAdd(&cB[s >> 3], 1);
        if (slotB < kSlice)
          binsB[((size_t)blk * kNumBins + (s >> 3)) * kSlice + slotB] =
              make_uint2(((unsigned)d << 8) | (s & 7), wu);
      }
    }
    __syncthreads();
    for (int t = tid; t < kNumBins; t += 1024) {      // contiguous row write
      cntA[(size_t)blk * kNumBins + t] = (unsigned short)min(cA[t], kSlice);
      cntB[(size_t)blk * kNumBins + t] = (unsigned short)min(cB[t], kSlice);
    }
  }

  // Transpose/tanh phase: blocks 0..N/64-1, one 64-node tile each.
  if (blk < (N >> 6)) {
    int n0 = blk * 64;
    for (int k = tid; k < 32 * 64; k += 1024) {       // coalesced 256B rows
      int b = k >> 6, n = k & 63;
      tile[b][n] = x[b * N + n0 + n];
    }
    __syncthreads();
    for (int k = tid; k < 64 * 32; k += 1024) {       // coalesced t-layout
      int n = k >> 5, b = k & 31;
      float xv = tile[b][n];
      int j = (n0 + n) * kB + b;
      x_t[j] = xv;
      fx_t[j] = tanhf(xv);
    }
  }
}

// ---- K2/K3: accum for one bin. Compact records to LDS, then pipelined
// gather + private per-half-wave replicas (no atomics), 32-way tree-sum. ----
__global__ void __launch_bounds__(1024) k_accum(
    const uint2* __restrict__ bins, const unsigned short* __restrict__ cnt,
    const float* __restrict__ vals, const float* __restrict__ x_t,
    const float* __restrict__ fx_t, float* __restrict__ eps_t,
    float* __restrict__ out, int N, int nrows, int mode) {
  __shared__ float rep[32 * kT * kPad];     // 36.9 KB replicas
  __shared__ uint2 stg[kStageCap];          // 10.2 KB compacted records
  __shared__ int cntL[kMaxRows];            // per-row counts
  __shared__ int scan[kMaxRows];            // inclusive prefix
  int tid = threadIdx.x, t = blockIdx.x;
  int b = tid & 31, slot = tid >> 5;        // 32 half-wave slots
  float* my = rep + slot * (kT * kPad);
#pragma unroll
  for (int l = 0; l < kT; l++) my[l * kPad + b] = 0.0f;   // private region

  // Load per-row counts (strided u16, L2-hot) and scan.
  if (tid < kMaxRows) {
    int c = (tid < nrows) ? (int)cnt[(size_t)tid * kNumBins + t] : 0;
    cntL[tid] = c;
    scan[tid] = c;
  }
  __syncthreads();
  for (int off = 1; off < kMaxRows; off <<= 1) {          // Hillis-Steele
    int v = 0;
    if (tid < kMaxRows && tid >= off) v = scan[tid - off];
    __syncthreads();
    if (tid < kMaxRows && tid >= off) scan[tid] += v;
    __syncthreads();
  }
  int T = min(scan[kMaxRows - 1], kStageCap);

  // Compact: one half-wave per row; lanes 0..c-1 copy contiguous records.
  for (int r = slot; r < nrows; r += 32) {
    int c = cntL[r];
    int base = scan[r] - c;                               // exclusive prefix
    if (b < c) {
      int p = base + b;
      if (p < kStageCap)
        stg[p] = bins[((size_t)r * kNumBins + t) * kSlice + b];
    }
  }
  __syncthreads();

  // Main loop: records from LDS, values gathered 2 iterations ahead.
  int i = slot;
  uint2 z = make_uint2(0u, 0u);
  uint2 r0 = (i      < T) ? stg[i]      : z;
  uint2 r1 = (i + 32 < T) ? stg[i + 32] : z;
  uint2 r2 = (i + 64 < T) ? stg[i + 64] : z;
  float v0 = (i      < T) ? vals[((r0.x >> 8) << kLogB) + b] : 0.0f;
  float v1 = (i + 32 < T) ? vals[((r1.x >> 8) << kLogB) + b] : 0.0f;
  while (i < T) {
    uint2 r3 = (i + 96 < T) ? stg[i + 96] : z;
    float v2 = (i + 64 < T) ? vals[((r2.x >> 8) << kLogB) + b] : 0.0f;
    my[(r0.x & 7) * kPad + b] += __uint_as_float(r0.y) * v0;  // 2-way max: free
    r0 = r1; r1 = r2; r2 = r3; v0 = v1; v1 = v2;
    i += 32;
  }
  __syncthreads();

  // Epilogue: 32-way tree-sum; bank = (4*local + bb) & 31 -> <=2-way (free).
  if (tid < kT * kB) {
    int local = tid & 7, bb = tid >> 3;     // local-fast: 32B store runs
    float s = 0.0f;
#pragma unroll
    for (int sl = 0; sl < 32; sl++) s += rep[sl * (kT * kPad) + local * kPad + bb];
    int n = t * kT + local;
    int j = n * kB + bb;
    if (mode == 0) {
      out[bb * N + n] = s;                  // mu (batch-major)
      eps_t[j] = x_t[j] - s;
    } else {
      float fx = fx_t[j];
      out[bb * N + n] = fmaf(1.0f - fx * fx, s, -eps_t[j]);   // dx
    }
  }
}

extern "C" void kernel_launch(void* const* d_in, const int* in_sizes, int n_in,
                              void* d_out, int out_size, void* d_ws, size_t ws_size,
                              hipStream_t stream) {
  const float* x    = (const float*)d_in[0];
  const float* w    = (const float*)d_in[1];
  const int*   esrc = (const int*)d_in[2];
  const int*   edst = (const int*)d_in[3];

  int BN = in_sizes[0];                // 131072
  int E  = in_sizes[1];                // 524288
  int N  = BN / kB;                    // 4096
  int nrows = (E + kChunkE - 1) / kChunkE;   // 256

  float* ws    = (float*)d_ws;
  float* x_t   = ws;                   // [BN]
  float* fx_t  = ws + (size_t)BN;      // [BN]
  float* eps_t = ws + 2 * (size_t)BN;  // [BN]
  unsigned short* cntA = (unsigned short*)(ws + 3 * (size_t)BN);  // [256*512]
  unsigned short* cntB = cntA + (size_t)kMaxRows * kNumBins;
  uint2* binsA = (uint2*)(cntB + (size_t)kMaxRows * kNumBins);    // 21 MB
  uint2* binsB = binsA + (size_t)kMaxRows * kNumBins * kSlice;    // 21 MB

  float* out_mu = (float*)d_out;
  float* out_dx = (float*)d_out + BN;

  int nblk1 = max(nrows, N >> 6);      // 256

  k_binit<<<nblk1, 1024, 0, stream>>>(x, w, esrc, edst, x_t, fx_t,
                                      binsA, binsB, cntA, cntB, N, E, nrows);
  // Pass 1: mu[dst] += w * fx[src]
  k_accum<<<kNumBins, 1024, 0, stream>>>(binsA, cntA, fx_t, x_t, fx_t,
                                         eps_t, out_mu, N, nrows, 0);
  // Pass 2: dxacc[src] += w * eps[dst]
  k_accum<<<kNumBins, 1024, 0, stream>>>(binsB, cntB, eps_t, x_t, fx_t,
                                         eps_t, out_dx, N, nrows, 1);
}